// Round 1
// baseline (762.291 us; speedup 1.0000x reference)
//
#include <hip/hip_runtime.h>
#include <math.h>

#define B_    256
#define NCH   32
#define T_    2000
#define NTF   4
#define NSF   40
#define NSUB  20
#define TK    25
#define NCLS  4
#define NTAN  210
#define NPAIR 820          // 40*41/2 packed upper triangle
#define ACC_STRIDE 860     // 820 gram + 40 column sums
#define TILE_T 250
#define NTILE  8           // 8 * 250 = 2000
#define PL     12

#define ACC_FLOATS (B_*ACC_STRIDE)
#define W2T_OFF ACC_FLOATS                    // 5120 floats, [c][s][f]
#define W1T_OFF (ACC_FLOATS + NSF*NTF*NCH)    // 100 floats,  [k][f]

#define XS_STRIDE 280      // 274 needed, padded
#define H2C_STRIDE 68      // 64 chunk + pad, 16B-aligned rows

__device__ __forceinline__ int pack_ut(int f, int g) {
    // f <= g, packed row-major upper triangle of 40x40
    return f*NSF - (f*(f-1))/2 + (g - f);
}

// ---------------- K0: weight transpose ----------------
__global__ void prep_kernel(const float* __restrict__ conv1_w,
                            const float* __restrict__ conv2_w,
                            float* __restrict__ ws) {
    int tid = threadIdx.x;
    float* w2t = ws + W2T_OFF;
    float* w1t = ws + W1T_OFF;
    for (int i = tid; i < NSF*NTF*NCH; i += 256) {
        int f = i & 3;
        int cs = i >> 2;
        int s = cs % NSF;
        int c = cs / NSF;
        w2t[i] = conv2_w[(s*NTF + f)*NCH + c];   // src layout [s][f][c]
    }
    for (int i = tid; i < NTF*TK; i += 256) {
        int f = i & 3;
        int k = i >> 2;
        w1t[i] = conv1_w[f*TK + k];              // src layout [f][k]
    }
}

// ---------------- K1: fused conv1+conv2+gram ----------------
__global__ __launch_bounds__(256, 2)
void conv_gram_kernel(const float* __restrict__ x,
                      const float* __restrict__ conv1_b,
                      const float* __restrict__ conv2_b,
                      const float* __restrict__ wts,   // ws (weights region)
                      float* __restrict__ acc)         // ws (accumulator region)
{
    __shared__ float xs[NCH*XS_STRIDE];       // 35.0 KB
    __shared__ float h2c[NSF*H2C_STRIDE];     // 10.6 KB

    const int tid  = threadIdx.x;
    const int bid  = blockIdx.x;
    const int b    = bid >> 3;
    const int tile = bid & 7;
    const int t0   = tile * TILE_T;

    // ---- stage x tile (with reflect padding at sequence edges) ----
    const float* xb = x + (size_t)b*NCH*T_;
    for (int li = tid; li < NCH*(TILE_T+TK-1); li += 256) {
        int c = li / (TILE_T+TK-1);
        int i = li - c*(TILE_T+TK-1);
        int tg = t0 + i - PL;
        tg = (tg < 0) ? -tg : tg;
        tg = (tg >= T_) ? (2*T_ - 2 - tg) : tg;
        xs[c*XS_STRIDE + i] = xb[c*T_ + tg];
    }
    __syncthreads();

    const float4* w1t = (const float4*)(wts + W1T_OFF);   // [k] -> f0..f3
    const float4* w2t = (const float4*)(wts + W2T_OFF);   // [c*40+s] -> f0..f3

    // ---- conv: one thread = one t, h2[40] in registers ----
    float h2acc[NSF];
    #pragma unroll
    for (int s = 0; s < NSF; ++s) h2acc[s] = conv2_b[s];

    const int tl = tid;                 // local t; valid if < TILE_T
    const float b1_0 = conv1_b[0], b1_1 = conv1_b[1], b1_2 = conv1_b[2], b1_3 = conv1_b[3];

    for (int c = 0; c < NCH; ++c) {
        const float* xr = xs + c*XS_STRIDE + tl;
        float a0 = b1_0, a1 = b1_1, a2 = b1_2, a3 = b1_3;
        #pragma unroll
        for (int k = 0; k < TK; ++k) {
            float xv = xr[k];
            float4 w = w1t[k];
            a0 = fmaf(xv, w.x, a0);
            a1 = fmaf(xv, w.y, a1);
            a2 = fmaf(xv, w.z, a2);
            a3 = fmaf(xv, w.w, a3);
        }
        const float4* wr = w2t + c*NSF;
        #pragma unroll
        for (int s = 0; s < NSF; ++s) {
            float4 w = wr[s];
            h2acc[s] = fmaf(w.x, a0, fmaf(w.y, a1, fmaf(w.z, a2, fmaf(w.w, a3, h2acc[s]))));
        }
    }
    if (tl >= TILE_T) {
        #pragma unroll
        for (int s = 0; s < NSF; ++s) h2acc[s] = 0.f;
    }

    // ---- gram: 2x2 tiles of the 20x20 block-upper-triangle (210 tiles) ----
    int bf = 0, bg = 0;
    if (tid < 210) {
        int rem = tid;
        while (rem >= NSUB - bf) { rem -= NSUB - bf; bf++; }
        bg = bf + rem;
    }
    float4 e00 = make_float4(0,0,0,0), e01 = e00, e10 = e00, e11 = e00;
    float csum = 0.f;

    for (int ch = 0; ch < 4; ++ch) {
        __syncthreads();
        if ((tid >> 6) == ch) {
            int tc = tid & 63;
            #pragma unroll
            for (int s = 0; s < NSF; ++s) h2c[s*H2C_STRIDE + tc] = h2acc[s];
        }
        __syncthreads();
        if (tid < 210) {
            const float4* r0 = (const float4*)(h2c + (2*bf  )*H2C_STRIDE);
            const float4* r1 = (const float4*)(h2c + (2*bf+1)*H2C_STRIDE);
            const float4* r2 = (const float4*)(h2c + (2*bg  )*H2C_STRIDE);
            const float4* r3 = (const float4*)(h2c + (2*bg+1)*H2C_STRIDE);
            #pragma unroll
            for (int q = 0; q < 16; ++q) {
                float4 a0 = r0[q], a1 = r1[q], b0 = r2[q], b1 = r3[q];
                e00.x = fmaf(a0.x, b0.x, e00.x); e00.y = fmaf(a0.y, b0.y, e00.y);
                e00.z = fmaf(a0.z, b0.z, e00.z); e00.w = fmaf(a0.w, b0.w, e00.w);
                e01.x = fmaf(a0.x, b1.x, e01.x); e01.y = fmaf(a0.y, b1.y, e01.y);
                e01.z = fmaf(a0.z, b1.z, e01.z); e01.w = fmaf(a0.w, b1.w, e01.w);
                e10.x = fmaf(a1.x, b0.x, e10.x); e10.y = fmaf(a1.y, b0.y, e10.y);
                e10.z = fmaf(a1.z, b0.z, e10.z); e10.w = fmaf(a1.w, b0.w, e10.w);
                e11.x = fmaf(a1.x, b1.x, e11.x); e11.y = fmaf(a1.y, b1.y, e11.y);
                e11.z = fmaf(a1.z, b1.z, e11.z); e11.w = fmaf(a1.w, b1.w, e11.w);
            }
        }
        if (tid < NSF) {
            const float4* rr = (const float4*)(h2c + tid*H2C_STRIDE);
            #pragma unroll
            for (int q = 0; q < 16; ++q) {
                float4 v = rr[q];
                csum += v.x + v.y + v.z + v.w;
            }
        }
    }

    float* accb = acc + b*ACC_STRIDE;
    if (tid < 210) {
        int f0 = 2*bf, f1 = 2*bf+1, g0 = 2*bg, g1 = 2*bg+1;
        float s00 = e00.x+e00.y+e00.z+e00.w;
        float s01 = e01.x+e01.y+e01.z+e01.w;
        float s10 = e10.x+e10.y+e10.z+e10.w;
        float s11 = e11.x+e11.y+e11.z+e11.w;
        atomicAdd(&accb[pack_ut(f0,g0)], s00);
        atomicAdd(&accb[pack_ut(f0,g1)], s01);
        if (bf != bg) atomicAdd(&accb[pack_ut(f1,g0)], s10);
        atomicAdd(&accb[pack_ut(f1,g1)], s11);
    }
    if (tid < NSF) atomicAdd(&accb[NPAIR + tid], csum);
}

// ---------------- K2: covariance -> bimap -> Jacobi eigh -> log -> head ----------------
__device__ __forceinline__ void jac_sched(int r, int k, int* p, int* q) {
    if (k == 0) { *p = 19; *q = r % 19; }
    else {
        *p = (r + k) % 19;
        *q = (r - k + 38) % 19;
    }
}

__global__ __launch_bounds__(64)
void finalize_kernel(const float* __restrict__ acc,
                     const float* __restrict__ W_bimap,
                     const float* __restrict__ clf_w,
                     const float* __restrict__ clf_b,
                     float* __restrict__ out)
{
    __shared__ double C[NSF*NSF];
    __shared__ double Wb[NSUB*NSF];
    __shared__ double M[NSUB*NSF];
    __shared__ double A[NSUB*21];
    __shared__ double V[NSUB*21];
    __shared__ double cs_c[10], cs_s[10];
    __shared__ double lam[NSUB];
    __shared__ double z[NTAN];

    const int tid = threadIdx.x;
    const int b   = blockIdx.x;
    const float* accb = acc + b*ACC_STRIDE;

    // C = (G - T mu mu^T) / (T-1)
    for (int i = tid; i < NSF*NSF; i += 64) {
        int f = i / NSF, g = i % NSF;
        int lo = f < g ? f : g;
        int hi = f < g ? g : f;
        double G  = (double)accb[pack_ut(lo, hi)];
        double sf = (double)accb[NPAIR + f];
        double sg = (double)accb[NPAIR + g];
        C[i] = (G - sf*sg/(double)T_) / (double)(T_ - 1);
    }
    for (int i = tid; i < NSUB*NSF; i += 64) Wb[i] = (double)W_bimap[i];
    __syncthreads();

    // M = Wb * C
    for (int i = tid; i < NSUB*NSF; i += 64) {
        int r = i / NSF, g = i % NSF;
        double s = 0.0;
        #pragma unroll 8
        for (int f = 0; f < NSF; ++f) s += Wb[r*NSF+f]*C[f*NSF+g];
        M[i] = s;
    }
    __syncthreads();

    // A = M * Wb^T ; V = I
    for (int i = tid; i < NSUB*NSUB; i += 64) {
        int r = i / NSUB, j = i % NSUB;
        double s = 0.0;
        #pragma unroll 8
        for (int g = 0; g < NSF; ++g) s += M[r*NSF+g]*Wb[j*NSF+g];
        A[r*21+j] = s;
        V[r*21+j] = (r == j) ? 1.0 : 0.0;
    }
    __syncthreads();

    // parallel-order cyclic Jacobi, fixed 12 sweeps, double precision
    for (int sweep = 0; sweep < 12; ++sweep) {
        for (int r = 0; r < 19; ++r) {
            if (tid < 10) {
                int p, q; jac_sched(r, tid, &p, &q);
                double app = A[p*21+p], aqq = A[q*21+q], apq = A[p*21+q];
                double c = 1.0, s = 0.0;
                if (fabs(apq) > 1e-300) {
                    double tau = (aqq - app) / (2.0*apq);
                    double t = ((tau >= 0.0) ? 1.0 : -1.0) / (fabs(tau) + sqrt(1.0 + tau*tau));
                    c = 1.0 / sqrt(1.0 + t*t);
                    s = t * c;
                }
                cs_c[tid] = c; cs_s[tid] = s;
            }
            __syncthreads();
            // row phase: rows p,q <- J^T applied on left (disjoint across pairs)
            for (int i = tid; i < 200; i += 64) {
                int k = i / 20, j = i % 20;
                int p, q; jac_sched(r, k, &p, &q);
                double c = cs_c[k], s = cs_s[k];
                double rp = A[p*21+j], rq = A[q*21+j];
                A[p*21+j] = c*rp - s*rq;
                A[q*21+j] = s*rp + c*rq;
            }
            __syncthreads();
            // column phase on A and V (disjoint across pairs)
            for (int i = tid; i < 200; i += 64) {
                int k = i / 20, row = i % 20;
                int p, q; jac_sched(r, k, &p, &q);
                double c = cs_c[k], s = cs_s[k];
                double cp = A[row*21+p], cq = A[row*21+q];
                A[row*21+p] = c*cp - s*cq;
                A[row*21+q] = s*cp + c*cq;
                double vp = V[row*21+p], vq = V[row*21+q];
                V[row*21+p] = c*vp - s*vq;
                V[row*21+q] = s*vp + c*vq;
            }
            __syncthreads();
        }
    }

    if (tid < NSUB) {
        double w = A[tid*21+tid];
        lam[tid] = log(fmax(w, 1e-4));   // REIG_EPS clamp + log (matrix-fn equivalence)
    }
    __syncthreads();

    // z = upper-tri of V diag(lam) V^T, off-diag * sqrt(2)
    for (int p = tid; p < NTAN; p += 64) {
        int i = 0, rem = p;
        while (rem >= NSUB - i) { rem -= NSUB - i; i++; }
        int j = i + rem;
        double s = 0.0;
        #pragma unroll 5
        for (int k = 0; k < NSUB; ++k) s += V[i*21+k]*lam[k]*V[j*21+k];
        z[p] = (i == j) ? s : s * 1.4142135623730951;
    }
    __syncthreads();

    if (tid < NCLS) {
        double s = (double)clf_b[tid];
        for (int p = 0; p < NTAN; ++p) s += (double)clf_w[tid*NTAN+p]*z[p];
        out[b*NCLS + tid] = (float)s;
    }
}

// ---------------- launch ----------------
extern "C" void kernel_launch(void* const* d_in, const int* in_sizes, int n_in,
                              void* d_out, int out_size, void* d_ws, size_t ws_size,
                              hipStream_t stream) {
    const float* x       = (const float*)d_in[0];
    const float* conv1_w = (const float*)d_in[1];
    const float* conv1_b = (const float*)d_in[2];
    const float* conv2_w = (const float*)d_in[3];
    const float* conv2_b = (const float*)d_in[4];
    const float* W_bimap = (const float*)d_in[5];
    const float* clf_w   = (const float*)d_in[6];
    const float* clf_b   = (const float*)d_in[7];
    float* out = (float*)d_out;
    float* ws  = (float*)d_ws;

    // zero the per-batch accumulators (ws is poisoned before every launch)
    hipMemsetAsync(ws, 0, (size_t)ACC_FLOATS*sizeof(float), stream);

    prep_kernel<<<1, 256, 0, stream>>>(conv1_w, conv2_w, ws);
    conv_gram_kernel<<<B_*NTILE, 256, 0, stream>>>(x, conv1_b, conv2_b, ws, ws);
    finalize_kernel<<<B_, 64, 0, stream>>>(ws, W_bimap, clf_w, clf_b, out);
}

// Round 2
// 431.485 us; speedup vs baseline: 1.7667x; 1.7667x over previous
//
#include <hip/hip_runtime.h>
#include <math.h>

#define B_    256
#define NCH   32
#define T_    2000
#define NTF   4
#define NSF   40
#define NSUB  20
#define TK    25
#define NCLS  4
#define NTAN  210
#define NPAIR 820          // 40*41/2 packed upper triangle
#define ACC_STRIDE 860     // 820 gram + 40 column sums
#define TILE_T 250
#define NTILE  8           // 8 * 250 = 2000
#define PL     12

#define ACC_FLOATS (B_*ACC_STRIDE)
#define W2T_OFF ACC_FLOATS                    // 5120 floats, [s][c][f]
#define W1T_OFF (ACC_FLOATS + NSF*NTF*NCH)    // 100 floats,  [k][f]

#define XS_STRIDE 280      // staged cols per channel (covers 274 needed)
#define H2_STRIDE 252      // 250 data + 2 zero pad; 63 float4; odd/8 group spread

__device__ __forceinline__ int pack_ut(int f, int g) {
    return f*NSF - (f*(f-1))/2 + (g - f);
}

// ---------------- K0: weight transpose ----------------
__global__ void prep_kernel(const float* __restrict__ conv1_w,
                            const float* __restrict__ conv2_w,
                            float* __restrict__ ws) {
    int tid = threadIdx.x;
    float* w2t = ws + W2T_OFF;   // [s][c][f] : ((s*32+c)*4+f)
    float* w1t = ws + W1T_OFF;   // [k][f]
    for (int i = tid; i < NSF*NTF*NCH; i += 256) {
        int f  = i & 3;
        int sc = i >> 2;
        int c  = sc & 31;
        int s  = sc >> 5;
        w2t[i] = conv2_w[(s*NTF + f)*NCH + c];   // src [s][f][c]
    }
    for (int i = tid; i < NTF*TK; i += 256) {
        int f = i & 3;
        int k = i >> 2;
        w1t[i] = conv1_w[f*TK + k];              // src [f][k]
    }
}

// ---------------- K1: fused conv1+conv2+gram ----------------
__global__ __launch_bounds__(256, 1)
void conv_gram_kernel(const float* __restrict__ x,
                      const float* __restrict__ conv1_b,
                      const float* __restrict__ conv2_b,
                      const float* __restrict__ wts,
                      float* __restrict__ acc)
{
    // union: xs[32][280] (35.8KB) during conv1, h2[40][252] (40.3KB) after
    __shared__ float lds[NSF*H2_STRIDE];
    float* xs = lds;
    float* h2 = lds;

    const int tid  = threadIdx.x;
    const int bid  = blockIdx.x;
    const int b    = bid >> 3;
    const int tile = bid & 7;
    const int t0   = tile * TILE_T;

    // ---- stage x tile (reflect padding), full 280 cols so no garbage ----
    const float* xb = x + (size_t)b*NCH*T_;
    for (int li = tid; li < NCH*XS_STRIDE; li += 256) {
        int c = li / XS_STRIDE;
        int i = li - c*XS_STRIDE;
        int tg = t0 + i - PL;
        tg = (tg < 0) ? -tg : tg;
        tg = (tg >= T_) ? (2*T_ - 2 - tg) : tg;
        xs[c*XS_STRIDE + i] = xb[c*T_ + tg];
    }
    __syncthreads();

    const float4* w1t = (const float4*)(wts + W1T_OFF);
    const float4* w2t = (const float4*)(wts + W2T_OFF);

    // ---- conv1: h1[c][f] in registers; k rolled, c unrolled ----
    float h1[NCH*NTF];
    {
        float b0 = conv1_b[0], b1 = conv1_b[1], b2 = conv1_b[2], b3 = conv1_b[3];
        #pragma unroll
        for (int c = 0; c < NCH; ++c) {
            h1[4*c+0] = b0; h1[4*c+1] = b1; h1[4*c+2] = b2; h1[4*c+3] = b3;
        }
    }
    #pragma clang loop unroll(disable)
    for (int k = 0; k < TK; ++k) {
        float4 w = w1t[k];
        #pragma unroll
        for (int c = 0; c < NCH; ++c) {
            float xv = xs[c*XS_STRIDE + tid + k];
            h1[4*c+0] = fmaf(xv, w.x, h1[4*c+0]);
            h1[4*c+1] = fmaf(xv, w.y, h1[4*c+1]);
            h1[4*c+2] = fmaf(xv, w.z, h1[4*c+2]);
            h1[4*c+3] = fmaf(xv, w.w, h1[4*c+3]);
        }
    }
    __syncthreads();   // xs dead; lds becomes h2

    // ---- conv2: s rolled (x2), c unrolled; write h2 rows to LDS ----
    #pragma clang loop unroll_count(2)
    for (int s = 0; s < NSF; ++s) {
        float a0 = conv2_b[s], a1 = 0.f, a2 = 0.f, a3 = 0.f;
        #pragma unroll
        for (int c = 0; c < NCH; ++c) {
            float4 w = w2t[s*NCH + c];
            a0 = fmaf(w.x, h1[4*c+0], a0);
            a1 = fmaf(w.y, h1[4*c+1], a1);
            a2 = fmaf(w.z, h1[4*c+2], a2);
            a3 = fmaf(w.w, h1[4*c+3], a3);
        }
        float v = (a0 + a1) + (a2 + a3);
        if (tid < H2_STRIDE) h2[s*H2_STRIDE + tid] = (tid < TILE_T) ? v : 0.f;
    }
    __syncthreads();

    // ---- gram: 2x2 tiles of 20x20 pair-blocks, full rows as float4 ----
    int bf = 0, bg = 0;
    if (tid < 210) {
        int rem = tid;
        while (rem >= NSUB - bf) { rem -= NSUB - bf; bf++; }
        bg = bf + rem;
    }
    float4 e00 = make_float4(0,0,0,0), e01 = e00, e10 = e00, e11 = e00;

    if (tid < 210) {
        const float4* r0 = (const float4*)(h2 + (2*bf  )*H2_STRIDE);
        const float4* r1 = (const float4*)(h2 + (2*bf+1)*H2_STRIDE);
        const float4* r2 = (const float4*)(h2 + (2*bg  )*H2_STRIDE);
        const float4* r3 = (const float4*)(h2 + (2*bg+1)*H2_STRIDE);
        #pragma unroll 7
        for (int q = 0; q < H2_STRIDE/4; ++q) {
            float4 a0 = r0[q], a1 = r1[q], b0 = r2[q], b1 = r3[q];
            e00.x = fmaf(a0.x, b0.x, e00.x); e00.y = fmaf(a0.y, b0.y, e00.y);
            e00.z = fmaf(a0.z, b0.z, e00.z); e00.w = fmaf(a0.w, b0.w, e00.w);
            e01.x = fmaf(a0.x, b1.x, e01.x); e01.y = fmaf(a0.y, b1.y, e01.y);
            e01.z = fmaf(a0.z, b1.z, e01.z); e01.w = fmaf(a0.w, b1.w, e01.w);
            e10.x = fmaf(a1.x, b0.x, e10.x); e10.y = fmaf(a1.y, b0.y, e10.y);
            e10.z = fmaf(a1.z, b0.z, e10.z); e10.w = fmaf(a1.w, b0.w, e10.w);
            e11.x = fmaf(a1.x, b1.x, e11.x); e11.y = fmaf(a1.y, b1.y, e11.y);
            e11.z = fmaf(a1.z, b1.z, e11.z); e11.w = fmaf(a1.w, b1.w, e11.w);
        }
    }
    float csum = 0.f;
    if (tid < NSF) {
        const float4* rr = (const float4*)(h2 + tid*H2_STRIDE);
        #pragma unroll 7
        for (int q = 0; q < H2_STRIDE/4; ++q) {
            float4 v = rr[q];
            csum += (v.x + v.y) + (v.z + v.w);
        }
    }

    float* accb = acc + b*ACC_STRIDE;
    if (tid < 210) {
        int f0 = 2*bf, f1 = 2*bf+1, g0 = 2*bg, g1 = 2*bg+1;
        float s00 = (e00.x+e00.y)+(e00.z+e00.w);
        float s01 = (e01.x+e01.y)+(e01.z+e01.w);
        float s10 = (e10.x+e10.y)+(e10.z+e10.w);
        float s11 = (e11.x+e11.y)+(e11.z+e11.w);
        atomicAdd(&accb[pack_ut(f0,g0)], s00);
        atomicAdd(&accb[pack_ut(f0,g1)], s01);
        if (bf != bg) atomicAdd(&accb[pack_ut(f1,g0)], s10);
        atomicAdd(&accb[pack_ut(f1,g1)], s11);
    }
    if (tid < NSF) atomicAdd(&accb[NPAIR + tid], csum);
}

// ---------------- K2: cov -> bimap -> fp32 Jacobi eigh -> log -> head ----------------
__global__ __launch_bounds__(64)
void finalize_kernel(const float* __restrict__ acc,
                     const float* __restrict__ W_bimap,
                     const float* __restrict__ clf_w,
                     const float* __restrict__ clf_b,
                     float* __restrict__ out)
{
    __shared__ float C[NSF*NSF];
    __shared__ float Wb[NSUB*NSF];
    __shared__ float M[NSUB*NSF];
    __shared__ float A[NSUB*21];
    __shared__ float V[NSUB*21];
    __shared__ float cs_c[10], cs_s[10];
    __shared__ float lam[NSUB];
    __shared__ float z[NTAN];

    const int tid = threadIdx.x;
    const int b   = blockIdx.x;
    const float* accb = acc + b*ACC_STRIDE;

    // C = (G - sf*sg/T) / (T-1), cancellation in double
    for (int i = tid; i < NSF*NSF; i += 64) {
        int f = i / NSF, g = i % NSF;
        int lo = f < g ? f : g;
        int hi = f < g ? g : f;
        double G  = (double)accb[pack_ut(lo, hi)];
        double sf = (double)accb[NPAIR + f];
        double sg = (double)accb[NPAIR + g];
        C[i] = (float)((G - sf*sg/(double)T_) / (double)(T_ - 1));
    }
    for (int i = tid; i < NSUB*NSF; i += 64) Wb[i] = W_bimap[i];
    __syncthreads();

    // M = Wb * C
    for (int i = tid; i < NSUB*NSF; i += 64) {
        int r = i / NSF, g = i % NSF;
        float s = 0.f;
        #pragma unroll 8
        for (int f = 0; f < NSF; ++f) s = fmaf(Wb[r*NSF+f], C[f*NSF+g], s);
        M[i] = s;
    }
    __syncthreads();

    // A = M * Wb^T ; V = I
    for (int i = tid; i < NSUB*NSUB; i += 64) {
        int r = i / NSUB, j = i % NSUB;
        float s = 0.f;
        #pragma unroll 8
        for (int g = 0; g < NSF; ++g) s = fmaf(M[r*NSF+g], Wb[j*NSF+g], s);
        A[r*21+j] = s;
        V[r*21+j] = (r == j) ? 1.f : 0.f;
    }
    __syncthreads();

    // hoisted (k,j) decode for the 4 strided work items
    int kk[4], jj[4], vv[4];
    #pragma unroll
    for (int it = 0; it < 4; ++it) {
        int i = tid + 64*it;
        vv[it] = (i < 200);
        kk[it] = i / 20;
        jj[it] = i - 20*(i/20);
    }

    // parallel-order cyclic Jacobi, fp32, 8 sweeps
    for (int sweep = 0; sweep < 8; ++sweep) {
        for (int r = 0; r < 19; ++r) {
            if (tid < 10) {
                int p, q;
                if (tid == 0) { p = 19; q = r; }
                else {
                    int a = r + tid;      if (a >= 19) a -= 19;
                    int d = r - tid + 19; if (d >= 19) d -= 19;
                    p = a; q = d;
                }
                float app = A[p*21+p], aqq = A[q*21+q], apq = A[p*21+q];
                float c = 1.f, s = 0.f;
                if (fabsf(apq) > 1e-30f) {
                    float tau = (aqq - app) / (2.f*apq);
                    float t = 1.f / (fabsf(tau) + sqrtf(1.f + tau*tau));
                    if (tau < 0.f) t = -t;
                    c = 1.f / sqrtf(1.f + t*t);
                    s = t * c;
                }
                cs_c[tid] = c; cs_s[tid] = s;
            }
            __syncthreads();
            // row phase
            #pragma unroll
            for (int it = 0; it < 4; ++it) if (vv[it]) {
                int k = kk[it], j = jj[it];
                int p, q;
                if (k == 0) { p = 19; q = r; }
                else {
                    int a = r + k;      if (a >= 19) a -= 19;
                    int d = r - k + 19; if (d >= 19) d -= 19;
                    p = a; q = d;
                }
                float c = cs_c[k], s = cs_s[k];
                float rp = A[p*21+j], rq = A[q*21+j];
                A[p*21+j] = c*rp - s*rq;
                A[q*21+j] = s*rp + c*rq;
            }
            __syncthreads();
            // column phase on A and V
            #pragma unroll
            for (int it = 0; it < 4; ++it) if (vv[it]) {
                int k = kk[it], row = jj[it];
                int p, q;
                if (k == 0) { p = 19; q = r; }
                else {
                    int a = r + k;      if (a >= 19) a -= 19;
                    int d = r - k + 19; if (d >= 19) d -= 19;
                    p = a; q = d;
                }
                float c = cs_c[k], s = cs_s[k];
                float cp = A[row*21+p], cq = A[row*21+q];
                A[row*21+p] = c*cp - s*cq;
                A[row*21+q] = s*cp + c*cq;
                float vp = V[row*21+p], vq = V[row*21+q];
                V[row*21+p] = c*vp - s*vq;
                V[row*21+q] = s*vp + c*vq;
            }
            __syncthreads();
        }
    }

    if (tid < NSUB) {
        float w = A[tid*21+tid];
        lam[tid] = logf(fmaxf(w, 1e-4f));
    }
    __syncthreads();

    // z = upper-tri of V diag(lam) V^T, off-diag * sqrt(2)
    for (int p = tid; p < NTAN; p += 64) {
        int i = 0, rem = p;
        while (rem >= NSUB - i) { rem -= NSUB - i; i++; }
        int j = i + rem;
        float s = 0.f;
        #pragma unroll 5
        for (int k = 0; k < NSUB; ++k) s = fmaf(V[i*21+k]*lam[k], V[j*21+k], s);
        z[p] = (i == j) ? s : s * 1.41421356237309515f;
    }
    __syncthreads();

    if (tid < NCLS) {
        float s = clf_b[tid];
        for (int p = 0; p < NTAN; ++p) s = fmaf(clf_w[tid*NTAN+p], z[p], s);
        out[b*NCLS + tid] = s;
    }
}

// ---------------- launch ----------------
extern "C" void kernel_launch(void* const* d_in, const int* in_sizes, int n_in,
                              void* d_out, int out_size, void* d_ws, size_t ws_size,
                              hipStream_t stream) {
    const float* x       = (const float*)d_in[0];
    const float* conv1_w = (const float*)d_in[1];
    const float* conv1_b = (const float*)d_in[2];
    const float* conv2_w = (const float*)d_in[3];
    const float* conv2_b = (const float*)d_in[4];
    const float* W_bimap = (const float*)d_in[5];
    const float* clf_w   = (const float*)d_in[6];
    const float* clf_b   = (const float*)d_in[7];
    float* out = (float*)d_out;
    float* ws  = (float*)d_ws;

    hipMemsetAsync(ws, 0, (size_t)ACC_FLOATS*sizeof(float), stream);

    prep_kernel<<<1, 256, 0, stream>>>(conv1_w, conv2_w, ws);
    conv_gram_kernel<<<B_*NTILE, 256, 0, stream>>>(x, conv1_b, conv2_b, ws, ws);
    finalize_kernel<<<B_, 64, 0, stream>>>(ws, W_bimap, clf_w, clf_b, out);
}

// Round 3
// 329.420 us; speedup vs baseline: 2.3140x; 1.3098x over previous
//
#include <hip/hip_runtime.h>
#include <math.h>

#define B_    256
#define NCH   32
#define T_    2000
#define NTF   4
#define NSF   40
#define NSUB  20
#define TK    25
#define NCLS  4
#define NTAN  210
#define NPAIR 820
#define ACC_STRIDE 860
#define TILE_T 250
#define NTILE  8
#define PL     12

#define ACC_FLOATS (B_*ACC_STRIDE)
#define W2T_OFF ACC_FLOATS                    // 5120 floats, [s][c][f]
#define W1T_OFF (ACC_FLOATS + NSF*NTF*NCH)    // 100 floats,  [k][f]

#define XS_TSTR 36         // dwords per t-row of xs[t][c]; 16B-aligned, 2-way banks
#define H2_STR  252        // h2[s][t]: 250 data + 2 zero pad
#define LDS_DW  10080      // max(280*36, 40*252) = 10080 dwords = 40320 B

typedef float v2f __attribute__((ext_vector_type(2)));

__device__ __forceinline__ v2f fma2(v2f a, v2f b, v2f c) {
#if __has_builtin(__builtin_elementwise_fma)
    return __builtin_elementwise_fma(a, b, c);
#else
    v2f r; r.x = fmaf(a.x, b.x, c.x); r.y = fmaf(a.y, b.y, c.y); return r;
#endif
}

__device__ __forceinline__ int pack_ut(int f, int g) {
    return f*NSF - (f*(f-1))/2 + (g - f);
}

// ---------------- K0: weight transpose ----------------
__global__ void prep_kernel(const float* __restrict__ conv1_w,
                            const float* __restrict__ conv2_w,
                            float* __restrict__ ws) {
    int tid = threadIdx.x;
    float* w2t = ws + W2T_OFF;   // [s][c][f]
    float* w1t = ws + W1T_OFF;   // [k][f]
    for (int i = tid; i < NSF*NTF*NCH; i += 256) {
        int f  = i & 3;
        int sc = i >> 2;
        int c  = sc & 31;
        int s  = sc >> 5;
        w2t[i] = conv2_w[(s*NTF + f)*NCH + c];
    }
    for (int i = tid; i < NTF*TK; i += 256) {
        int f = i & 3;
        int k = i >> 2;
        w1t[i] = conv1_w[f*TK + k];
    }
}

// ---------------- K1: fused conv1+conv2+gram ----------------
__global__ __launch_bounds__(256, 2)
void conv_gram_kernel(const float* __restrict__ x,
                      const float* __restrict__ conv1_b,
                      const float* __restrict__ conv2_b,
                      const float* __restrict__ wts,
                      float* __restrict__ acc)
{
    __shared__ float lds[LDS_DW];   // union: xs[280][36] then h2[40][252]

    const int tid  = threadIdx.x;
    const int bid  = blockIdx.x;
    const int b    = bid >> 3;
    const int tile = bid & 7;
    const int t0   = tile * TILE_T;

    // ---- stage x transposed: xs[i][c] at lds[i*36+c], i in [0,280) ----
    const float* xb = x + (size_t)b*NCH*T_;
    for (int li = tid; li < NCH*280; li += 256) {
        int c = li / 280;
        int i = li - c*280;
        int tg = t0 + i - PL;
        tg = (tg < 0) ? -tg : tg;
        tg = (tg >= T_) ? (2*T_ - 2 - tg) : tg;
        lds[i*XS_TSTR + c] = xb[c*T_ + tg];
    }
    __syncthreads();

    const float4* w1t = (const float4*)(wts + W1T_OFF);
    const float4* w2t = (const float4*)(wts + W2T_OFF);

    // ---- conv1: h1[c][f] as v2f pairs; per k read 32 channels as 8 b128 ----
    v2f h1[64];
    {
        float b0 = conv1_b[0], b1 = conv1_b[1], b2 = conv1_b[2], b3 = conv1_b[3];
        #pragma unroll
        for (int c = 0; c < NCH; ++c) {
            v2f lo; lo.x = b0; lo.y = b1;
            v2f hi; hi.x = b2; hi.y = b3;
            h1[2*c]   = lo;
            h1[2*c+1] = hi;
        }
    }
    #pragma clang loop unroll(disable)
    for (int k = 0; k < TK; ++k) {
        float4 wq = w1t[k];
        v2f w01; w01.x = wq.x; w01.y = wq.y;
        v2f w23; w23.x = wq.z; w23.y = wq.w;
        const float4* xr = (const float4*)&lds[(tid + k)*XS_TSTR];
        float4 xv4[8];
        #pragma unroll
        for (int j = 0; j < 8; ++j) xv4[j] = xr[j];
        const float* xv = (const float*)xv4;
        #pragma unroll
        for (int c = 0; c < NCH; ++c) {
            v2f xc; xc.x = xv[c]; xc.y = xv[c];
            h1[2*c]   = fma2(xc, w01, h1[2*c]);
            h1[2*c+1] = fma2(xc, w23, h1[2*c+1]);
        }
    }
    __syncthreads();   // xs dead; lds becomes h2

    // ---- conv2: s rolled x2; write h2[s][t] rows ----
    #pragma clang loop unroll_count(2)
    for (int s = 0; s < NSF; ++s) {
        v2f a01; a01.x = conv2_b[s]; a01.y = 0.f;
        v2f a23; a23.x = 0.f;        a23.y = 0.f;
        #pragma unroll
        for (int c = 0; c < NCH; ++c) {
            float4 wq = w2t[s*NCH + c];
            v2f w01; w01.x = wq.x; w01.y = wq.y;
            v2f w23; w23.x = wq.z; w23.y = wq.w;
            a01 = fma2(w01, h1[2*c],   a01);
            a23 = fma2(w23, h1[2*c+1], a23);
        }
        float v = (a01.x + a01.y) + (a23.x + a23.y);
        if (tid < H2_STR) lds[s*H2_STR + tid] = (tid < TILE_T) ? v : 0.f;
    }
    __syncthreads();

    float* accb = acc + b*ACC_STRIDE;

    // ---- gram: 4x4 row-block tiles, 55 threads (wave 0) ----
    if (tid < 55) {
        int bf = 0, rem = tid;
        while (rem >= 10 - bf) { rem -= 10 - bf; bf++; }
        int bg = bf + rem;

        const float4* rA[4];
        const float4* rB[4];
        #pragma unroll
        for (int a = 0; a < 4; ++a) {
            rA[a] = (const float4*)&lds[(4*bf + a)*H2_STR];
            rB[a] = (const float4*)&lds[(4*bg + a)*H2_STR];
        }
        v2f accL[16], accH[16];
        #pragma unroll
        for (int i = 0; i < 16; ++i) { accL[i] = (v2f)0.f; accH[i] = (v2f)0.f; }

        #pragma unroll 7
        for (int q = 0; q < H2_STR/4; ++q) {
            float4 av[4], bv[4];
            #pragma unroll
            for (int a = 0; a < 4; ++a) av[a] = rA[a][q];
            #pragma unroll
            for (int a = 0; a < 4; ++a) bv[a] = rB[a][q];
            #pragma unroll
            for (int a = 0; a < 4; ++a) {
                v2f aL; aL.x = av[a].x; aL.y = av[a].y;
                v2f aH; aH.x = av[a].z; aH.y = av[a].w;
                #pragma unroll
                for (int g = 0; g < 4; ++g) {
                    v2f bL; bL.x = bv[g].x; bL.y = bv[g].y;
                    v2f bH; bH.x = bv[g].z; bH.y = bv[g].w;
                    accL[a*4+g] = fma2(aL, bL, accL[a*4+g]);
                    accH[a*4+g] = fma2(aH, bH, accH[a*4+g]);
                }
            }
        }
        #pragma unroll
        for (int a = 0; a < 4; ++a) {
            #pragma unroll
            for (int g = 0; g < 4; ++g) {
                int f  = 4*bf + a;
                int gg = 4*bg + g;
                if (f <= gg) {
                    v2f sL = accL[a*4+g], sH = accH[a*4+g];
                    float s = (sL.x + sL.y) + (sH.x + sH.y);
                    atomicAdd(&accb[pack_ut(f, gg)], s);
                }
            }
        }
    }

    // ---- column sums: wave 1 ----
    if (tid >= 64 && tid < 64 + NSF) {
        int row = tid - 64;
        const float4* rr = (const float4*)&lds[row*H2_STR];
        float csum = 0.f;
        #pragma unroll 7
        for (int q = 0; q < H2_STR/4; ++q) {
            float4 v = rr[q];
            csum += (v.x + v.y) + (v.z + v.w);
        }
        atomicAdd(&accb[NPAIR + row], csum);
    }
}

// ---------------- K2: cov -> bimap -> fused 2x2-block Jacobi -> log -> head ----------------
__device__ __forceinline__ void pq_sched(int r, int k, int& p, int& q) {
    if (k == 0) { p = 19; q = r; }
    else {
        int a = r + k;      if (a >= 19) a -= 19;
        int d = r - k + 19; if (d >= 19) d -= 19;
        p = a; q = d;
    }
}

__global__ __launch_bounds__(128)
void finalize_kernel(const float* __restrict__ acc,
                     const float* __restrict__ W_bimap,
                     const float* __restrict__ clf_w,
                     const float* __restrict__ clf_b,
                     float* __restrict__ out)
{
    __shared__ float C[NSF*NSF];
    __shared__ float Wb[NSUB*NSF];
    __shared__ float M[NSUB*NSF];
    __shared__ float A[NSUB*21];
    __shared__ float V[NSUB*21];
    __shared__ float cs_c[10], cs_s[10];
    __shared__ float lam[NSUB];
    __shared__ float z[NTAN];

    const int tid = threadIdx.x;
    const int b   = blockIdx.x;
    const float* accb = acc + b*ACC_STRIDE;

    for (int i = tid; i < NSF*NSF; i += 128) {
        int f = i / NSF, g = i % NSF;
        int lo = f < g ? f : g;
        int hi = f < g ? g : f;
        double G  = (double)accb[pack_ut(lo, hi)];
        double sf = (double)accb[NPAIR + f];
        double sg = (double)accb[NPAIR + g];
        C[i] = (float)((G - sf*sg/(double)T_) / (double)(T_ - 1));
    }
    for (int i = tid; i < NSUB*NSF; i += 128) Wb[i] = W_bimap[i];
    __syncthreads();

    for (int i = tid; i < NSUB*NSF; i += 128) {
        int r = i / NSF, g = i % NSF;
        float s = 0.f;
        #pragma unroll 8
        for (int f = 0; f < NSF; ++f) s = fmaf(Wb[r*NSF+f], C[f*NSF+g], s);
        M[i] = s;
    }
    __syncthreads();

    for (int i = tid; i < NSUB*NSUB; i += 128) {
        int r = i / NSUB, j = i % NSUB;
        float s = 0.f;
        #pragma unroll 8
        for (int g = 0; g < NSF; ++g) s = fmaf(M[r*NSF+g], Wb[j*NSF+g], s);
        A[r*21+j] = s;
        V[r*21+j] = (r == j) ? 1.f : 0.f;
    }
    __syncthreads();

    const int kk = tid / 10;
    const int ll = tid - 10*(tid/10);

    for (int sweep = 0; sweep < 7; ++sweep) {
        for (int r = 0; r < 19; ++r) {
            if (tid < 10) {
                int p, q; pq_sched(r, tid, p, q);
                float app = A[p*21+p], aqq = A[q*21+q], apq = A[p*21+q];
                float c = 1.f, s = 0.f;
                if (fabsf(apq) > 1e-30f) {
                    float tau = (aqq - app) / (2.f*apq);
                    float t = 1.f / (fabsf(tau) + sqrtf(1.f + tau*tau));
                    if (tau < 0.f) t = -t;
                    c = 1.f / sqrtf(1.f + t*t);
                    s = t * c;
                }
                cs_c[tid] = c; cs_s[tid] = s;
            }
            __syncthreads();
            if (tid < 100) {
                int pk, qk, pl, ql;
                pq_sched(r, kk, pk, qk);
                pq_sched(r, ll, pl, ql);
                float ck = cs_c[kk], sk = cs_s[kk];
                float cl = cs_c[ll], sl = cs_s[ll];
                // A block rows {pk,qk} x cols {pl,ql}
                float a00 = A[pk*21+pl], a01 = A[pk*21+ql];
                float a10 = A[qk*21+pl], a11 = A[qk*21+ql];
                // rows: p' = ck*p - sk*q ; q' = sk*p + ck*q
                float t00 = ck*a00 - sk*a10, t01 = ck*a01 - sk*a11;
                float t10 = sk*a00 + ck*a10, t11 = sk*a01 + ck*a11;
                // cols: p' = cl*p - sl*q ; q' = sl*p + cl*q
                A[pk*21+pl] = cl*t00 - sl*t01;
                A[pk*21+ql] = sl*t00 + cl*t01;
                A[qk*21+pl] = cl*t10 - sl*t11;
                A[qk*21+ql] = sl*t10 + cl*t11;
                // V: only column rotation; rows {pk,qk} are a partition of 0..19
                float v00 = V[pk*21+pl], v01 = V[pk*21+ql];
                float v10 = V[qk*21+pl], v11 = V[qk*21+ql];
                V[pk*21+pl] = cl*v00 - sl*v01;
                V[pk*21+ql] = sl*v00 + cl*v01;
                V[qk*21+pl] = cl*v10 - sl*v11;
                V[qk*21+ql] = sl*v10 + cl*v11;
            }
            __syncthreads();
        }
    }

    if (tid < NSUB) {
        float w = A[tid*21+tid];
        lam[tid] = logf(fmaxf(w, 1e-4f));
    }
    __syncthreads();

    for (int p = tid; p < NTAN; p += 128) {
        int i = 0, rem = p;
        while (rem >= NSUB - i) { rem -= NSUB - i; i++; }
        int j = i + rem;
        float s = 0.f;
        #pragma unroll 5
        for (int k = 0; k < NSUB; ++k) s = fmaf(V[i*21+k]*lam[k], V[j*21+k], s);
        z[p] = (i == j) ? s : s * 1.41421356237309515f;
    }
    __syncthreads();

    if (tid < NCLS) {
        float s = clf_b[tid];
        for (int p = 0; p < NTAN; ++p) s = fmaf(clf_w[tid*NTAN+p], z[p], s);
        out[b*NCLS + tid] = s;
    }
}

// ---------------- launch ----------------
extern "C" void kernel_launch(void* const* d_in, const int* in_sizes, int n_in,
                              void* d_out, int out_size, void* d_ws, size_t ws_size,
                              hipStream_t stream) {
    const float* x       = (const float*)d_in[0];
    const float* conv1_w = (const float*)d_in[1];
    const float* conv1_b = (const float*)d_in[2];
    const float* conv2_w = (const float*)d_in[3];
    const float* conv2_b = (const float*)d_in[4];
    const float* W_bimap = (const float*)d_in[5];
    const float* clf_w   = (const float*)d_in[6];
    const float* clf_b   = (const float*)d_in[7];
    float* out = (float*)d_out;
    float* ws  = (float*)d_ws;

    hipMemsetAsync(ws, 0, (size_t)ACC_FLOATS*sizeof(float), stream);

    prep_kernel<<<1, 256, 0, stream>>>(conv1_w, conv2_w, ws);
    conv_gram_kernel<<<B_*NTILE, 256, 0, stream>>>(x, conv1_b, conv2_b, ws, ws);
    finalize_kernel<<<B_, 128, 0, stream>>>(ws, W_bimap, clf_w, clf_b, out);
}